// Round 4
// baseline (38.722 us; speedup 1.0000x reference)
//
#include <hip/hip_runtime.h>

constexpr int B_ = 4;
constexpr int L_ = 4096;
constexpr int D_ = 128;
constexpr int K_ = 16;
constexpr int NKEY = 2 * K_;          // 32 candidates max
constexpr int GATHER_BLOCKS = 2048;   // 8 blocks/CU on 256 CUs
constexpr int F4_TOTAL = B_ * L_ * K_ * (D_ / 4);       // 8,388,608 float4
constexpr int F4_PER_BLOCK = F4_TOTAL / GATHER_BLOCKS;  // 4096
constexpr int GATHER_ITERS = F4_PER_BLOCK / 256;        // 16

typedef float f32x4 __attribute__((ext_vector_type(4)));  // clang vector:
// __builtin_nontemporal_* requires a real vector type, not HIP_vector_type.

static __device__ __forceinline__ int imin(int a, int b) { return a < b ? a : b; }
static __device__ __forceinline__ int imax(int a, int b) { return a > b ? a : b; }

// ---------------- kernel 1: exact top-K search, one query per thread -------
// Packs (dist, idx) into a single int key = (dist<<12)|idx  (dist < 2^18,
// idx < 2^12), so ascending key order == ascending (dist, idx) — exactly
// jax.lax.top_k's tie-breaking. Writes keys into out_dist's storage (as int);
// the gather kernel converts them to float distances in place each call.
__global__ __launch_bounds__(64) void nbr_search_kernel(
    const int* __restrict__ fi, int* __restrict__ keyout)
{
    const int q = blockIdx.x * 64 + threadIdx.x;     // [0, B*L)
    const int b = q >> 12;
    const int i = q & (L_ - 1);
    const int* __restrict__ c = fi + b * L_;
    const int ci = c[i];

    // greedy two-pointer: exact 16-wide window holding the 16-smallest
    // distance multiset (contains ALL elements with dist < T)
    int lo = i, hi = i;
    #pragma unroll
    for (int t = 0; t < K_ - 1; ++t) {
        int dl = (lo > 0)      ? (ci - c[lo - 1]) : 0x7FFFFFFF;
        int dr = (hi < L_ - 1) ? (c[hi + 1] - ci) : 0x7FFFFFFF;
        if (dl <= dr) --lo; else ++hi;
    }
    const int T = imax(ci - c[lo], c[hi] - ci);

    int keys[NKEY];                    // static-indexed only (no scratch)
    #pragma unroll
    for (int t = 0; t < K_; ++t) {
        int j = lo + t;
        int v = c[j];
        int d = (v < ci) ? (ci - v) : (v - ci);
        keys[t] = (d << 12) | j;
    }

    // left tie-run: elements of value ci-T left of the window have dist == T
    // with SMALLER indices than any in-window tie -> top_k can prefer them.
    const int vL = ci - T;
    int j0 = -1;
    if (c[lo] == vL) j0 = lo;
    else if (lo > 0 && c[lo - 1] == vL) j0 = lo - 1;
    #pragma unroll
    for (int t = 0; t < K_; ++t) keys[K_ + t] = 0x7FFFFFFF;
    if (j0 >= 0) {
        int p = j0;
        while (p > 0 && c[p - 1] == vL) --p;         // run start (min index)
        const int e = imin(lo - 1, p + (K_ - 1));
        #pragma unroll
        for (int t = 0; t < K_; ++t) {
            int j = p + t;
            if (j <= e) keys[K_ + t] = (T << 12) | j;
        }
    }

    // bitonic sort, 32 keys, fully unrolled (static indices -> registers)
    #pragma unroll
    for (int size = 2; size <= NKEY; size <<= 1) {
        #pragma unroll
        for (int stride = size >> 1; stride > 0; stride >>= 1) {
            #pragma unroll
            for (int x = 0; x < NKEY; ++x) {
                int y = x ^ stride;
                if (y > x) {
                    bool up = ((x & size) == 0);
                    int a = keys[x], bb = keys[y];
                    int mn = imin(a, bb), mx = imax(a, bb);
                    keys[x] = up ? mn : mx;
                    keys[y] = up ? mx : mn;
                }
            }
        }
    }

    int4* ko = (int4*)(keyout + (size_t)q * K_);
    ko[0] = make_int4(keys[0],  keys[1],  keys[2],  keys[3]);
    ko[1] = make_int4(keys[4],  keys[5],  keys[6],  keys[7]);
    ko[2] = make_int4(keys[8],  keys[9],  keys[10], keys[11]);
    ko[3] = make_int4(keys[12], keys[13], keys[14], keys[15]);
}

// ---------------- kernel 2: streaming gather, XCD-swizzled ----------------
// Each block copies a CONTIGUOUS 4096-float4 (64 KB) output slice; the XCD
// swizzle gives each XCD a contiguous q-range so its attr working set
// (~1 MB) fits the 4 MB per-XCD L2. 32 lanes handle one K-row (512 B).
// Output stores are NON-TEMPORAL: out_attr is write-once/never-re-read, so
// bypassing L2 keeps attr resident instead of being evicted by 134 MB of
// write-allocate traffic.
__global__ __launch_bounds__(256) void nbr_gather_kernel(
    const float* __restrict__ attr, float* __restrict__ out_dist,
    float* __restrict__ out_attr)
{
    const int bid  = blockIdx.x;
    const int sbid = (bid & 7) * (GATHER_BLOCKS / 8) + (bid >> 3);
    const int tid  = threadIdx.x;
    const int* __restrict__ keys = (const int*)out_dist;  // same storage
    const size_t base = (size_t)sbid * F4_PER_BLOCK;

    #pragma unroll 4
    for (int it = 0; it < GATHER_ITERS; ++it) {
        size_t f4 = base + (size_t)it * 256 + tid;
        int row = (int)(f4 >> 5);          // global (q,k) row, 32 f4 per row
        int off = (int)(f4 & 31);
        int key = keys[row];               // broadcast across the 32 lanes
        int j   = key & (L_ - 1);
        int bb  = row >> 16;               // row / (L_*K_)
        const f32x4* __restrict__ src =
            (const f32x4*)attr + ((size_t)bb * L_ + j) * (D_ / 4);
        f32x4 v = src[off];
        __builtin_nontemporal_store(v, (f32x4*)out_attr + f4);
        if (off == 0)                      // finalize distance in place
            __builtin_nontemporal_store((float)(key >> 12), out_dist + row);
    }
}

extern "C" void kernel_launch(void* const* d_in, const int* in_sizes, int n_in,
                              void* d_out, int out_size, void* d_ws, size_t ws_size,
                              hipStream_t stream) {
    const int*   fi   = (const int*)d_in[0];     // [B, L, 1] int32 (sorted per b)
    const float* attr = (const float*)d_in[1];   // [B, L, D] float32
    float* out      = (float*)d_out;
    float* out_dist = out;                        // [B, L, K, 1]
    float* out_attr = out + (size_t)B_ * L_ * K_; // [B, L, K, D]

    nbr_search_kernel<<<dim3(B_ * L_ / 64), dim3(64), 0, stream>>>(
        fi, (int*)out_dist);
    nbr_gather_kernel<<<dim3(GATHER_BLOCKS), dim3(256), 0, stream>>>(
        attr, out_dist, out_attr);
}

// Round 5
// 32.212 us; speedup vs baseline: 1.2021x; 1.2021x over previous
//
#include <hip/hip_runtime.h>

typedef float f32x4 __attribute__((ext_vector_type(4)));

constexpr int B_ = 4;
constexpr int L_ = 4096;
constexpr int D_ = 128;
constexpr int K_ = 16;
constexpr int NKEY = 2 * K_;            // 32 candidates max
constexpr int QPB = 8;                  // queries per block
constexpr int BLOCKS = B_ * L_ / QPB;   // 2048 (8 per CU)

static __device__ __forceinline__ int imin(int a, int b) { return a < b ? a : b; }
static __device__ __forceinline__ int imax(int a, int b) { return a > b ? a : b; }

// Fused: block = 8 consecutive queries. Lanes 0..7 of wave 0 run the exact
// top-K search in SIMD lockstep (one search per lane), write out_dist and
// the neighbor indices to LDS; after one barrier all 256 threads stream the
// 8 x 16 attr rows (addresses from LDS -> no global dependent-load chain).
__global__ __launch_bounds__(256) void fused_nbr_kernel(
    const int* __restrict__ fi, const float* __restrict__ attr,
    float* __restrict__ out_dist, float* __restrict__ out_attr)
{
    __shared__ int s_nbr[QPB * K_];     // [q_local*16 + k] = neighbor row j

    const int bid  = blockIdx.x;
    const int sbid = (bid & 7) * (BLOCKS / 8) + (bid >> 3);  // XCD-contiguous
    const int q0   = sbid * QPB;        // first query of this block
    const int b    = q0 >> 12;          // q0 / L_ (QPB divides L_)
    const int* __restrict__ c = fi + b * L_;
    const int tid = threadIdx.x;

    if (tid < QPB) {
        const int i  = (q0 & (L_ - 1)) + tid;
        const int ci = c[i];

        // greedy two-pointer: 16-wide window holding the 16-smallest
        // distance multiset (contains ALL elements with dist < T)
        int lo = i, hi = i;
        #pragma unroll
        for (int t = 0; t < K_ - 1; ++t) {
            int dl = (lo > 0)      ? (ci - c[lo - 1]) : 0x7FFFFFFF;
            int dr = (hi < L_ - 1) ? (c[hi + 1] - ci) : 0x7FFFFFFF;
            if (dl <= dr) --lo; else ++hi;
        }
        const int T = imax(ci - c[lo], c[hi] - ci);

        // key = (dist<<12)|idx : ascending key == ascending (dist, idx),
        // exactly jax.lax.top_k tie-breaking (dist < 2^18, idx < 2^12).
        int keys[NKEY];
        #pragma unroll
        for (int t = 0; t < K_; ++t) {
            int j = lo + t;
            int v = c[j];
            int d = (v < ci) ? (ci - v) : (v - ci);
            keys[t] = (d << 12) | j;
        }

        // left tie-run (value ci-T, indices < window) can win the tie-break
        const int vL = ci - T;
        int j0 = -1;
        if (c[lo] == vL) j0 = lo;
        else if (lo > 0 && c[lo - 1] == vL) j0 = lo - 1;
        #pragma unroll
        for (int t = 0; t < K_; ++t) keys[K_ + t] = 0x7FFFFFFF;
        if (j0 >= 0) {
            int p = j0;
            while (p > 0 && c[p - 1] == vL) --p;     // run start (min index)
            const int e = imin(lo - 1, p + (K_ - 1));
            #pragma unroll
            for (int t = 0; t < K_; ++t) {
                int j = p + t;
                if (j <= e) keys[K_ + t] = (T << 12) | j;
            }
        }

        // bitonic sort, 32 keys, fully unrolled (registers only)
        #pragma unroll
        for (int size = 2; size <= NKEY; size <<= 1) {
            #pragma unroll
            for (int stride = size >> 1; stride > 0; stride >>= 1) {
                #pragma unroll
                for (int x = 0; x < NKEY; ++x) {
                    int y = x ^ stride;
                    if (y > x) {
                        bool up = ((x & size) == 0);
                        int a = keys[x], bb = keys[y];
                        int mn = imin(a, bb), mx = imax(a, bb);
                        keys[x] = up ? mn : mx;
                        keys[y] = up ? mx : mn;
                    }
                }
            }
        }

        // emit: neighbor rows -> LDS, distances -> out_dist (exact float)
        float* od = out_dist + (size_t)(q0 + tid) * K_;
        #pragma unroll
        for (int t = 0; t < K_; ++t) {
            s_nbr[tid * K_ + t] = keys[t] & (L_ - 1);
            od[t] = (float)(keys[t] >> 12);
        }
    }
    __syncthreads();

    // streaming gather: 128 rows x 512 B, contiguous 64 KB output slice.
    // 32 lanes per row; addresses come from LDS so loads issue back-to-back.
    const f32x4* __restrict__ ab = (const f32x4*)(attr + (size_t)b * L_ * D_);
    f32x4* __restrict__ dst = (f32x4*)out_attr + (size_t)q0 * (K_ * D_ / 4);
    const int lane = tid & 31, grp = tid >> 5;   // grp in 0..7
    #pragma unroll 8
    for (int it = 0; it < 16; ++it) {
        int row = it * 8 + grp;                  // 0..127 = q_local*16 + k
        int j = s_nbr[row];                      // broadcast per 32-lane group
        dst[(size_t)row * 32 + lane] = ab[(size_t)j * 32 + lane];
    }
}

extern "C" void kernel_launch(void* const* d_in, const int* in_sizes, int n_in,
                              void* d_out, int out_size, void* d_ws, size_t ws_size,
                              hipStream_t stream) {
    const int*   fi   = (const int*)d_in[0];     // [B, L, 1] int32 (sorted per b)
    const float* attr = (const float*)d_in[1];   // [B, L, D] float32
    float* out      = (float*)d_out;
    float* out_dist = out;                        // [B, L, K, 1]
    float* out_attr = out + (size_t)B_ * L_ * K_; // [B, L, K, D]

    fused_nbr_kernel<<<dim3(BLOCKS), dim3(256), 0, stream>>>(
        fi, attr, out_dist, out_attr);
}